// Round 1
// baseline (372.465 us; speedup 1.0000x reference)
//
// Inputs f32 (+ int32 edge_index), output f32, bf16 MFMA internally.
// R13: fused kernel re-tiled to 16 nodes/wave (grid 391->782 blocks, ~3
// waves/SIMD instead of 1.5 -- it was grid-limited latency-bound at 14%
// occupancy). combine folded into pull (meanY buffer + 1 launch removed).
#include <hip/hip_runtime.h>
#include <hip/hip_bf16.h>

typedef __attribute__((ext_vector_type(8))) short bf16x8;
typedef __attribute__((ext_vector_type(4))) short s16x4;
typedef __attribute__((ext_vector_type(4))) float f32x4;
typedef unsigned short u16;
typedef unsigned int u32;

#define D 128      // D_IN == D_H
#define DC 256     // concat dim
// LDS tile: 16 rows x 128 u16, XOR-swizzled (16B-aligned, low bank conflict)
#define SWZ(row, dim) (((row) << 7) + ((dim) ^ (((row) & 15) << 3)))

__device__ __forceinline__ float bf2f(u16 b) {
    u32 u = ((u32)b) << 16;
    return __uint_as_float(u);
}
__device__ __forceinline__ u16 f2bf(float f) {
    u32 u = __float_as_uint(f);
    u32 r = (u + 0x7fffu + ((u >> 16) & 1u)) >> 16;   // RNE
    return (u16)r;
}
__device__ __forceinline__ float sigmoidf_(float x) {
    float e = __builtin_amdgcn_exp2f(-1.4426950408889634f * x);
    return __builtin_amdgcn_rcpf(1.0f + e);
}
__device__ __forceinline__ bf16x8 cvt8(const float* __restrict__ p) {
    f32x4 lo = *(const f32x4*)p;
    f32x4 hi = *(const f32x4*)(p + 4);
    union { bf16x8 v; u16 s[8]; } u;
#pragma unroll
    for (int i = 0; i < 4; i++) {
        u.s[i]     = f2bf(lo[i]);
        u.s[i + 4] = f2bf(hi[i]);
    }
    return u.v;
}

// Fused prep: 6 weight transposes (f32->bf16) + xb=bf16(x) + degree histogram.
__global__ __launch_bounds__(256) void prep_kernel(
    const float* __restrict__ Wxr, const float* __restrict__ Whr,
    const float* __restrict__ Wxz, const float* __restrict__ Whz,
    const float* __restrict__ Wl,  const float* __restrict__ Wr,
    u16* __restrict__ WxrT, u16* __restrict__ WhrT,
    u16* __restrict__ WxzT, u16* __restrict__ WhzT,
    u16* __restrict__ WlT,  u16* __restrict__ WrT,
    const float* __restrict__ x, u16* __restrict__ xb,
    const int* __restrict__ ei, int* __restrict__ deg,
    int N, int E, int nbx)
{
    int bid = blockIdx.x;
    int tid = threadIdx.x;
    if (bid < 256) {                       // 4 gate weights, 128x128 each
        int m = bid >> 6;
        int g = (bid & 63) * 256 + tid;
        const float* W = (m == 0) ? Wxr : (m == 1) ? Whr : (m == 2) ? Wxz : Whz;
        u16* Wt        = (m == 0) ? WxrT : (m == 1) ? WhrT : (m == 2) ? WxzT : WhzT;
        int k = g >> 7, n = g & 127;
        Wt[n * D + k] = f2bf(W[g]);
    } else if (bid < 512) {                // Wl / Wr, 256x128 each
        int m = (bid - 256) >> 7;
        int g = ((bid - 256) & 127) * 256 + tid;
        const float* W = (m == 0) ? Wl : Wr;
        u16* Wt        = (m == 0) ? WlT : WrT;
        int k = g >> 7, n = g & 127;
        Wt[n * DC + k] = f2bf(W[g]);
    } else if (bid < 512 + nbx) {          // xb = bf16(x)
        long long g = (long long)(bid - 512) * 256 + tid;
        if (g < (long long)N * D) xb[g] = f2bf(x[g]);
    } else {                               // histogram of dst
        long long e = (long long)(bid - 512 - nbx) * 256 + tid;
        if (e < E) atomicAdd(&deg[ei[(size_t)E + e]], 1);
    }
}

// ---- parallel exclusive scan of deg -> rstart ----
__global__ __launch_bounds__(256) void scan1_kernel(
    const int* __restrict__ deg, int* __restrict__ rstart,
    int* __restrict__ bsum, int N)
{
    __shared__ int tmp[256];
    int t = threadIdx.x;
    int g = blockIdx.x * 256 + t;
    int v = (g < N) ? deg[g] : 0;
    tmp[t] = v;
    __syncthreads();
#pragma unroll
    for (int s = 1; s < 256; s <<= 1) {
        int add = (t >= s) ? tmp[t - s] : 0;
        __syncthreads();
        tmp[t] += add;
        __syncthreads();
    }
    if (g < N) rstart[g] = tmp[t] - v;
    if (t == 255) bsum[blockIdx.x] = tmp[255];
}

__global__ __launch_bounds__(256) void scan2_kernel(int* __restrict__ bsum, int nb)
{
    __shared__ int tmp[256];
    int t = threadIdx.x;
    int v = (t < nb) ? bsum[t] : 0;
    tmp[t] = v;
    __syncthreads();
#pragma unroll
    for (int s = 1; s < 256; s <<= 1) {
        int add = (t >= s) ? tmp[t - s] : 0;
        __syncthreads();
        tmp[t] += add;
        __syncthreads();
    }
    if (t < nb) bsum[t] = tmp[t] - v;
}

__global__ __launch_bounds__(256) void scan3_kernel(
    int* __restrict__ rstart, const int* __restrict__ bsum,
    int* __restrict__ fillc, int N)
{
    int g = blockIdx.x * 256 + threadIdx.x;
    if (g < N) {
        rstart[g] += bsum[blockIdx.x];
        fillc[g] = 0;
    }
}

__global__ void fill_kernel(const int* __restrict__ ei, const int* __restrict__ row_start,
                            int* __restrict__ fillc, int* __restrict__ col, int E) {
    int e = blockIdx.x * 256 + threadIdx.x;
    if (e >= E) return;
    int src = ei[e], dst = ei[(size_t)E + e];
    int pos = atomicAdd(&fillc[dst], 1);
    col[row_start[dst] + pos] = src;
}

// ---- fused: gates (r,z) -> rh in LDS -> y=[xb|rh]@Wl, w=[xb|rh]@Wr ----
// One wave handles 16 nodes (1 MFMA tile). Grid = ceil(N/64) blocks of 4
// waves -> ~3 waves/SIMD co-resident (was 1.5 at 32 nodes/wave).
__global__ __launch_bounds__(256) void fused_kernel(
    const u16* __restrict__ xb, const float* __restrict__ h,
    const u16* __restrict__ WxrT, const u16* __restrict__ WhrT,
    const u16* __restrict__ WxzT, const u16* __restrict__ WhzT,
    const u16* __restrict__ WlT,  const u16* __restrict__ WrT,
    const float* __restrict__ bxr, const float* __restrict__ bxz,
    u16* __restrict__ zo, u16* __restrict__ yo, u16* __restrict__ wo, int N)
{
    __shared__ u16 lds[4][16 * 128];   // per wave: 1 node-tile, 4KB
    const int wave = threadIdx.x >> 6;
    const int lane = threadIdx.x & 63;
    const int quad = lane >> 4;
    const int l15  = lane & 15;
    const int node0 = blockIdx.x * 64 + wave * 16;
    if (node0 >= N) return;
    u16* Lt = lds[wave];

    // stage h tile (bf16, swizzled) into LDS — coalesced f32 reads
#pragma unroll
    for (int it = 0; it < 4; it++) {
        int idx = it * 64 + lane;
        int row = idx >> 4, seg = idx & 15;       // seg = 8-dim chunk
        int node = node0 + row; if (node >= N) node = N - 1;
        bf16x8 hv = cvt8(h + (size_t)node * D + seg * 8);
        *(bf16x8*)&Lt[SWZ(row, seg * 8)] = hv;
    }

    // xb A-frags (global) and h A-frags (LDS)
    bf16x8 ax[4], ah[4];
    {
        int arow = node0 + l15; if (arow >= N) arow = N - 1;
        const u16* xp = xb + (size_t)arow * D + quad * 8;
#pragma unroll
        for (int c = 0; c < 4; c++) {
            ax[c] = *(const bf16x8*)(xp + c * 32);
            ah[c] = *(const bf16x8*)&Lt[SWZ(l15, c * 32 + quad * 8)];
        }
    }

    // ---- gates phase ----
#pragma unroll
    for (int nt = 0; nt < 8; nt++) {
        f32x4 ar = {0.f,0.f,0.f,0.f};
        f32x4 az = {0.f,0.f,0.f,0.f};
        const u16* wrx = WxrT + (size_t)(nt * 16 + l15) * D + quad * 8;
        const u16* wrh = WhrT + (size_t)(nt * 16 + l15) * D + quad * 8;
        const u16* wzx = WxzT + (size_t)(nt * 16 + l15) * D + quad * 8;
        const u16* wzh = WhzT + (size_t)(nt * 16 + l15) * D + quad * 8;
#pragma unroll
        for (int c = 0; c < 4; c++) {
            bf16x8 b0 = *(const bf16x8*)(wrx + c * 32);
            bf16x8 b1 = *(const bf16x8*)(wrh + c * 32);
            bf16x8 b2 = *(const bf16x8*)(wzx + c * 32);
            bf16x8 b3 = *(const bf16x8*)(wzh + c * 32);
            ar = __builtin_amdgcn_mfma_f32_16x16x32_bf16(ax[c], b0, ar, 0, 0, 0);
            ar = __builtin_amdgcn_mfma_f32_16x16x32_bf16(ah[c], b1, ar, 0, 0, 0);
            az = __builtin_amdgcn_mfma_f32_16x16x32_bf16(ax[c], b2, az, 0, 0, 0);
            az = __builtin_amdgcn_mfma_f32_16x16x32_bf16(ah[c], b3, az, 0, 0, 0);
        }
        int dim = nt * 16 + l15;
        float br = bxr[dim];
        float bz = bxz[dim];
#pragma unroll
        for (int reg = 0; reg < 4; reg++) {
            int row = quad * 4 + reg;
            int node = node0 + row;
            float hv = bf2f(Lt[SWZ(row, dim)]);
            float r  = sigmoidf_(ar[reg] + br);
            float zz = sigmoidf_(az[reg] + bz);
            Lt[SWZ(row, dim)] = f2bf(r * hv);       // rh in place of h
            if (node < N) zo[(size_t)node * D + dim] = f2bf(zz);
        }
    }

    // rh A-fragments from LDS (C-layout -> A-layout transform)
    bf16x8 arh[4];
#pragma unroll
    for (int c = 0; c < 4; c++)
        arh[c] = *(const bf16x8*)&Lt[SWZ(l15, c * 32 + quad * 8)];

    // ---- proj phase: y (Wl) -> LDS (coalesced store later), w (Wr) -> scattered ----
#pragma unroll
    for (int nt = 0; nt < 8; nt++) {
        f32x4 ay = {0.f,0.f,0.f,0.f};
        f32x4 aw = {0.f,0.f,0.f,0.f};
        const u16* pl = WlT + (size_t)(nt * 16 + l15) * DC + quad * 8;
        const u16* pr = WrT + (size_t)(nt * 16 + l15) * DC + quad * 8;
#pragma unroll
        for (int c = 0; c < 4; c++) {
            bf16x8 l0 = *(const bf16x8*)(pl + c * 32);
            bf16x8 l1 = *(const bf16x8*)(pl + 128 + c * 32);
            bf16x8 r0 = *(const bf16x8*)(pr + c * 32);
            bf16x8 r1 = *(const bf16x8*)(pr + 128 + c * 32);
            ay = __builtin_amdgcn_mfma_f32_16x16x32_bf16(ax[c],  l0, ay, 0, 0, 0);
            ay = __builtin_amdgcn_mfma_f32_16x16x32_bf16(arh[c], l1, ay, 0, 0, 0);
            aw = __builtin_amdgcn_mfma_f32_16x16x32_bf16(ax[c],  r0, aw, 0, 0, 0);
            aw = __builtin_amdgcn_mfma_f32_16x16x32_bf16(arh[c], r1, aw, 0, 0, 0);
        }
        int dim = nt * 16 + l15;
#pragma unroll
        for (int reg = 0; reg < 4; reg++) {
            int row = quad * 4 + reg;
            int node = node0 + row;
            Lt[SWZ(row, dim)] = f2bf(ay[reg]);   // y over rh (dead)
            if (node < N) wo[(size_t)node * D + dim] = f2bf(aw[reg]);
        }
    }

    // store y coalesced from LDS
#pragma unroll
    for (int it = 0; it < 4; it++) {
        int idx = it * 64 + lane;
        int row = idx >> 4, seg = idx & 15;
        int node = node0 + row;
        if (node < N)
            *(bf16x8*)(yo + (size_t)node * D + seg * 8) = *(const bf16x8*)&Lt[SWZ(row, seg * 8)];
    }
}

// ---- pull+combine: out[n] = (1-z)*(meanY + bl + w) + z*h  (1 wave/node) ----
__global__ __launch_bounds__(256) void pull_kernel(
    const int* __restrict__ row_start, const int* __restrict__ deg,
    const int* __restrict__ col, const u16* __restrict__ y,
    const u16* __restrict__ z, const u16* __restrict__ w,
    const float* __restrict__ h, const float* __restrict__ bl,
    float* __restrict__ out, int N)
{
    const int wave = threadIdx.x >> 6;
    const int lane = threadIdx.x & 63;
    const int node = blockIdx.x * 4 + wave;
    if (node >= N) return;

    const int base = row_start[node];
    const int d    = deg[node];
    const int g    = lane >> 4;
    const int l15  = lane & 15;

    float a[8] = {0.f,0.f,0.f,0.f,0.f,0.f,0.f,0.f};
    for (int i = 0; i < d; i += 4) {
        int e = i + g;
        if (e < d) {
            int s = col[base + e];
            bf16x8 v = *(const bf16x8*)(y + (size_t)s * D + l15 * 8);
#pragma unroll
            for (int j = 0; j < 8; j++) a[j] += bf2f((u16)v[j]);
        }
    }
#pragma unroll
    for (int j = 0; j < 8; j++) {
        a[j] += __shfl_xor(a[j], 16, 64);
        a[j] += __shfl_xor(a[j], 32, 64);
    }
    if (lane < 16) {
        float inv = 1.0f / (float)(d > 0 ? d : 1);
        size_t o16 = (size_t)node * D + l15 * 8;
        bf16x8 zv = *(const bf16x8*)(z + o16);
        bf16x8 wv = *(const bf16x8*)(w + o16);
        f32x4 h0 = *(const f32x4*)(h + o16);
        f32x4 h1 = *(const f32x4*)(h + o16 + 4);
        f32x4 b0 = *(const f32x4*)(bl + l15 * 8);
        f32x4 b1 = *(const f32x4*)(bl + l15 * 8 + 4);
        f32x4 o0, o1;
#pragma unroll
        for (int j = 0; j < 4; j++) {
            float zz = bf2f((u16)zv[j]);
            float nv = a[j] * inv + b0[j] + bf2f((u16)wv[j]);
            o0[j] = (1.0f - zz) * nv + zz * h0[j];
        }
#pragma unroll
        for (int j = 0; j < 4; j++) {
            float zz = bf2f((u16)zv[j + 4]);
            float nv = a[j + 4] * inv + b1[j] + bf2f((u16)wv[j + 4]);
            o1[j] = (1.0f - zz) * nv + zz * h1[j];
        }
        *(f32x4*)(out + o16)     = o0;
        *(f32x4*)(out + o16 + 4) = o1;
    }
}

extern "C" void kernel_launch(void* const* d_in, const int* in_sizes, int n_in,
                              void* d_out, int out_size, void* d_ws, size_t ws_size,
                              hipStream_t stream)
{
    const float* x   = (const float*)d_in[0];
    const int*   ei  = (const int*)d_in[1];
    const float* h   = (const float*)d_in[2];
    const float* Wxr = (const float*)d_in[3];
    const float* bxr = (const float*)d_in[4];
    const float* Whr = (const float*)d_in[5];
    const float* Wxz = (const float*)d_in[6];
    const float* bxz = (const float*)d_in[7];
    const float* Whz = (const float*)d_in[8];
    const float* Wl  = (const float*)d_in[9];
    const float* bl  = (const float*)d_in[10];
    const float* Wr  = (const float*)d_in[11];
    float* out = (float*)d_out;

    const int N = in_sizes[0] / D;
    const int E = in_sizes[1] / 2;
    if (N <= 0 || E <= 0) return;

    const int nbn = (N + 255) / 256;
    if (nbn > 256) return;                  // scan2 capacity; N=50000 ok

    char* ws = (char*)d_ws;
    size_t off = 0;
    auto alloc = [&](size_t bytes) -> void* {
        void* p = ws + off;
        off += (bytes + 255) & ~(size_t)255;
        return p;
    };
    u16*   z     = (u16*)  alloc((size_t)N * D * 2);
    u16*   xbuf  = (u16*)  alloc((size_t)N * D * 2);
    u16*   y     = (u16*)  alloc((size_t)N * D * 2);
    u16*   w     = (u16*)  alloc((size_t)N * D * 2);
    int*   deg   = (int*)  alloc((size_t)N * 4);
    int*   rstart= (int*)  alloc((size_t)N * 4);
    int*   fillc = (int*)  alloc((size_t)N * 4);
    int*   bsum  = (int*)  alloc((size_t)256 * 4);
    int*   col   = (int*)  alloc((size_t)E * 4);
    u16*   WxrT  = (u16*)  alloc((size_t)D * D * 2);
    u16*   WhrT  = (u16*)  alloc((size_t)D * D * 2);
    u16*   WxzT  = (u16*)  alloc((size_t)D * D * 2);
    u16*   WhzT  = (u16*)  alloc((size_t)D * D * 2);
    u16*   WlT   = (u16*)  alloc((size_t)DC * D * 2);
    u16*   WrT   = (u16*)  alloc((size_t)DC * D * 2);
    (void)n_in; (void)out_size;
    if (off > ws_size) return;   // clean failure instead of OOB fault

    hipMemsetAsync(deg, 0, (size_t)N * 4, stream);

    const int nbx = (N * D + 255) / 256;
    const int nbh = (E + 255) / 256;
    prep_kernel<<<512 + nbx + nbh, 256, 0, stream>>>(
        Wxr, Whr, Wxz, Whz, Wl, Wr,
        WxrT, WhrT, WxzT, WhzT, WlT, WrT,
        x, xbuf, ei, deg, N, E, nbx);

    scan1_kernel<<<nbn, 256, 0, stream>>>(deg, rstart, bsum, N);
    scan2_kernel<<<1, 256, 0, stream>>>(bsum, nbn);
    scan3_kernel<<<nbn, 256, 0, stream>>>(rstart, bsum, fillc, N);
    fill_kernel<<<nbh, 256, 0, stream>>>(ei, rstart, fillc, col, E);

    fused_kernel<<<(N + 63) / 64, 256, 0, stream>>>(
        xbuf, h, WxrT, WhrT, WxzT, WhzT, WlT, WrT, bxr, bxz, z, y, w, N);

    pull_kernel<<<(N + 3) / 4, 256, 0, stream>>>(
        rstart, deg, col, y, z, w, h, bl, out, N);
}

// Round 2
// 295.190 us; speedup vs baseline: 1.2618x; 1.2618x over previous
//
// Inputs f32 (+ int32 edge_index), output f32, bf16 MFMA internally.
// R14: fused kernel restructured to kill weight re-streaming (R12/R13 were
// weight-L2-BW bound at ~5-6 TB/s: time scaled linearly with weight bytes).
// Block = 512 thr / 8 waves / 128 nodes; wave w owns output-dim slice nt=w
// and computes it for all 8 node tiles -> each weight fragment loaded once
// per block, reused by 8 MFMAs. Weight traffic 800 MB -> 100 MB.
#include <hip/hip_runtime.h>
#include <hip/hip_bf16.h>

typedef __attribute__((ext_vector_type(8))) short bf16x8;
typedef __attribute__((ext_vector_type(4))) short s16x4;
typedef __attribute__((ext_vector_type(4))) float f32x4;
typedef unsigned short u16;
typedef unsigned int u32;

#define D 128      // D_IN == D_H
#define DC 256     // concat dim
// LDS tile: 16 rows x 128 u16, XOR-swizzled (16B-aligned, low bank conflict)
#define SWZ(row, dim) (((row) << 7) + ((dim) ^ (((row) & 15) << 3)))

__device__ __forceinline__ float bf2f(u16 b) {
    u32 u = ((u32)b) << 16;
    return __uint_as_float(u);
}
__device__ __forceinline__ u16 f2bf(float f) {
    u32 u = __float_as_uint(f);
    u32 r = (u + 0x7fffu + ((u >> 16) & 1u)) >> 16;   // RNE
    return (u16)r;
}
__device__ __forceinline__ float sigmoidf_(float x) {
    float e = __builtin_amdgcn_exp2f(-1.4426950408889634f * x);
    return __builtin_amdgcn_rcpf(1.0f + e);
}
__device__ __forceinline__ bf16x8 cvt8(const float* __restrict__ p) {
    f32x4 lo = *(const f32x4*)p;
    f32x4 hi = *(const f32x4*)(p + 4);
    union { bf16x8 v; u16 s[8]; } u;
#pragma unroll
    for (int i = 0; i < 4; i++) {
        u.s[i]     = f2bf(lo[i]);
        u.s[i + 4] = f2bf(hi[i]);
    }
    return u.v;
}

// Fused prep: 6 weight transposes (f32->bf16) + xb=bf16(x) + degree histogram.
__global__ __launch_bounds__(256) void prep_kernel(
    const float* __restrict__ Wxr, const float* __restrict__ Whr,
    const float* __restrict__ Wxz, const float* __restrict__ Whz,
    const float* __restrict__ Wl,  const float* __restrict__ Wr,
    u16* __restrict__ WxrT, u16* __restrict__ WhrT,
    u16* __restrict__ WxzT, u16* __restrict__ WhzT,
    u16* __restrict__ WlT,  u16* __restrict__ WrT,
    const float* __restrict__ x, u16* __restrict__ xb,
    const int* __restrict__ ei, int* __restrict__ deg,
    int N, int E, int nbx)
{
    int bid = blockIdx.x;
    int tid = threadIdx.x;
    if (bid < 256) {                       // 4 gate weights, 128x128 each
        int m = bid >> 6;
        int g = (bid & 63) * 256 + tid;
        const float* W = (m == 0) ? Wxr : (m == 1) ? Whr : (m == 2) ? Wxz : Whz;
        u16* Wt        = (m == 0) ? WxrT : (m == 1) ? WhrT : (m == 2) ? WxzT : WhzT;
        int k = g >> 7, n = g & 127;
        Wt[n * D + k] = f2bf(W[g]);
    } else if (bid < 512) {                // Wl / Wr, 256x128 each
        int m = (bid - 256) >> 7;
        int g = ((bid - 256) & 127) * 256 + tid;
        const float* W = (m == 0) ? Wl : Wr;
        u16* Wt        = (m == 0) ? WlT : WrT;
        int k = g >> 7, n = g & 127;
        Wt[n * DC + k] = f2bf(W[g]);
    } else if (bid < 512 + nbx) {          // xb = bf16(x)
        long long g = (long long)(bid - 512) * 256 + tid;
        if (g < (long long)N * D) xb[g] = f2bf(x[g]);
    } else {                               // histogram of dst
        long long e = (long long)(bid - 512 - nbx) * 256 + tid;
        if (e < E) atomicAdd(&deg[ei[(size_t)E + e]], 1);
    }
}

// ---- parallel exclusive scan of deg -> rstart ----
__global__ __launch_bounds__(256) void scan1_kernel(
    const int* __restrict__ deg, int* __restrict__ rstart,
    int* __restrict__ bsum, int N)
{
    __shared__ int tmp[256];
    int t = threadIdx.x;
    int g = blockIdx.x * 256 + t;
    int v = (g < N) ? deg[g] : 0;
    tmp[t] = v;
    __syncthreads();
#pragma unroll
    for (int s = 1; s < 256; s <<= 1) {
        int add = (t >= s) ? tmp[t - s] : 0;
        __syncthreads();
        tmp[t] += add;
        __syncthreads();
    }
    if (g < N) rstart[g] = tmp[t] - v;
    if (t == 255) bsum[blockIdx.x] = tmp[255];
}

__global__ __launch_bounds__(256) void scan2_kernel(int* __restrict__ bsum, int nb)
{
    __shared__ int tmp[256];
    int t = threadIdx.x;
    int v = (t < nb) ? bsum[t] : 0;
    tmp[t] = v;
    __syncthreads();
#pragma unroll
    for (int s = 1; s < 256; s <<= 1) {
        int add = (t >= s) ? tmp[t - s] : 0;
        __syncthreads();
        tmp[t] += add;
        __syncthreads();
    }
    if (t < nb) bsum[t] = tmp[t] - v;
}

__global__ __launch_bounds__(256) void scan3_kernel(
    int* __restrict__ rstart, const int* __restrict__ bsum,
    int* __restrict__ fillc, int N)
{
    int g = blockIdx.x * 256 + threadIdx.x;
    if (g < N) {
        rstart[g] += bsum[blockIdx.x];
        fillc[g] = 0;
    }
}

__global__ void fill_kernel(const int* __restrict__ ei, const int* __restrict__ row_start,
                            int* __restrict__ fillc, int* __restrict__ col, int E) {
    int e = blockIdx.x * 256 + threadIdx.x;
    if (e >= E) return;
    int src = ei[e], dst = ei[(size_t)E + e];
    int pos = atomicAdd(&fillc[dst], 1);
    col[row_start[dst] + pos] = src;
}

// ---- fused: gates (r,z) -> rh in LDS -> y=[xb|rh]@Wl, w=[xb|rh]@Wr ----
// 512 threads = 8 waves; 128 nodes (8 tiles of 16) per block.
// Wave w computes output dims [w*16, w*16+16) for ALL 8 tiles, so each
// weight fragment is loaded once per block and reused by 8 MFMAs.
__global__ __launch_bounds__(512) void fused_kernel(
    const u16* __restrict__ xb, const float* __restrict__ h,
    const u16* __restrict__ WxrT, const u16* __restrict__ WhrT,
    const u16* __restrict__ WxzT, const u16* __restrict__ WhzT,
    const u16* __restrict__ WlT,  const u16* __restrict__ WrT,
    const float* __restrict__ bxr, const float* __restrict__ bxz,
    u16* __restrict__ zo, u16* __restrict__ yo, u16* __restrict__ wo, int N)
{
    __shared__ u16 hT[8][16 * 128];    // h tiles, bf16 swizzled (read-only in gates)
    __shared__ u16 rhT[8][16 * 128];   // r*h tiles (written in gates, read in proj)
    const int wave = threadIdx.x >> 6;
    const int lane = threadIdx.x & 63;
    const int quad = lane >> 4;
    const int l15  = lane & 15;
    const int node0 = blockIdx.x * 128;
    if (node0 >= N) return;

    // stage h tile `wave` (coalesced f32 reads -> bf16 swizzled LDS)
    {
        u16* Lh = hT[wave];
        int tb = node0 + wave * 16;
#pragma unroll
        for (int it = 0; it < 4; it++) {
            int idx = it * 64 + lane;
            int row = idx >> 4, seg = idx & 15;       // seg = 8-dim chunk
            int node = tb + row; if (node >= N) node = N - 1;
            *(bf16x8*)&Lh[SWZ(row, seg * 8)] = cvt8(h + (size_t)node * D + seg * 8);
        }
    }
    __syncthreads();

    const int nt  = wave;            // this wave's output-dim slice
    const int dim = nt * 16 + l15;

    // ---- gates phase: r,z for all 8 tiles at dims [nt*16, nt*16+16) ----
    {
        const u16* wrx = WxrT + (size_t)(nt * 16 + l15) * D + quad * 8;
        const u16* wrh = WhrT + (size_t)(nt * 16 + l15) * D + quad * 8;
        const u16* wzx = WxzT + (size_t)(nt * 16 + l15) * D + quad * 8;
        const u16* wzh = WhzT + (size_t)(nt * 16 + l15) * D + quad * 8;
        bf16x8 b0[4], b1[4], b2[4], b3[4];
#pragma unroll
        for (int c = 0; c < 4; c++) {
            b0[c] = *(const bf16x8*)(wrx + c * 32);
            b1[c] = *(const bf16x8*)(wrh + c * 32);
            b2[c] = *(const bf16x8*)(wzx + c * 32);
            b3[c] = *(const bf16x8*)(wzh + c * 32);
        }
        float br = bxr[dim];
        float bz = bxz[dim];
#pragma unroll 2
        for (int t = 0; t < 8; t++) {
            const u16* Lh = hT[t];
            int tb = node0 + t * 16;
            int arow = tb + l15; if (arow >= N) arow = N - 1;
            const u16* xp = xb + (size_t)arow * D + quad * 8;
            bf16x8 ax[4], ah[4];
#pragma unroll
            for (int c = 0; c < 4; c++) {
                ax[c] = *(const bf16x8*)(xp + c * 32);
                ah[c] = *(const bf16x8*)&Lh[SWZ(l15, c * 32 + quad * 8)];
            }
            f32x4 ar = {0.f,0.f,0.f,0.f};
            f32x4 az = {0.f,0.f,0.f,0.f};
#pragma unroll
            for (int c = 0; c < 4; c++) {
                ar = __builtin_amdgcn_mfma_f32_16x16x32_bf16(ax[c], b0[c], ar, 0, 0, 0);
                ar = __builtin_amdgcn_mfma_f32_16x16x32_bf16(ah[c], b1[c], ar, 0, 0, 0);
                az = __builtin_amdgcn_mfma_f32_16x16x32_bf16(ax[c], b2[c], az, 0, 0, 0);
                az = __builtin_amdgcn_mfma_f32_16x16x32_bf16(ah[c], b3[c], az, 0, 0, 0);
            }
            u16* Lrh = rhT[t];
#pragma unroll
            for (int reg = 0; reg < 4; reg++) {
                int row = quad * 4 + reg;
                int node = tb + row;
                float hv = bf2f(Lh[SWZ(row, dim)]);
                float r  = sigmoidf_(ar[reg] + br);
                float zz = sigmoidf_(az[reg] + bz);
                Lrh[SWZ(row, dim)] = f2bf(r * hv);
                if (node < N) zo[(size_t)node * D + dim] = f2bf(zz);
            }
        }
    }
    __syncthreads();   // all rh tiles complete

    // ---- proj phase: y = [xb|rh] @ Wl, w = [xb|rh] @ Wr at this wave's dims ----
    {
        const u16* pl = WlT + (size_t)(nt * 16 + l15) * DC + quad * 8;
        const u16* pr = WrT + (size_t)(nt * 16 + l15) * DC + quad * 8;
        bf16x8 l0[4], l1[4], r0[4], r1[4];
#pragma unroll
        for (int c = 0; c < 4; c++) {
            l0[c] = *(const bf16x8*)(pl + c * 32);
            l1[c] = *(const bf16x8*)(pl + 128 + c * 32);
            r0[c] = *(const bf16x8*)(pr + c * 32);
            r1[c] = *(const bf16x8*)(pr + 128 + c * 32);
        }
#pragma unroll 2
        for (int t = 0; t < 8; t++) {
            const u16* Lrh = rhT[t];
            int tb = node0 + t * 16;
            int arow = tb + l15; if (arow >= N) arow = N - 1;
            const u16* xp = xb + (size_t)arow * D + quad * 8;
            bf16x8 ax[4], arh[4];
#pragma unroll
            for (int c = 0; c < 4; c++) {
                ax[c]  = *(const bf16x8*)(xp + c * 32);
                arh[c] = *(const bf16x8*)&Lrh[SWZ(l15, c * 32 + quad * 8)];
            }
            f32x4 ay = {0.f,0.f,0.f,0.f};
            f32x4 aw = {0.f,0.f,0.f,0.f};
#pragma unroll
            for (int c = 0; c < 4; c++) {
                ay = __builtin_amdgcn_mfma_f32_16x16x32_bf16(ax[c],  l0[c], ay, 0, 0, 0);
                ay = __builtin_amdgcn_mfma_f32_16x16x32_bf16(arh[c], l1[c], ay, 0, 0, 0);
                aw = __builtin_amdgcn_mfma_f32_16x16x32_bf16(ax[c],  r0[c], aw, 0, 0, 0);
                aw = __builtin_amdgcn_mfma_f32_16x16x32_bf16(arh[c], r1[c], aw, 0, 0, 0);
            }
#pragma unroll
            for (int reg = 0; reg < 4; reg++) {
                int row = quad * 4 + reg;
                int node = tb + row;
                if (node < N) {
                    yo[(size_t)node * D + dim] = f2bf(ay[reg]);
                    wo[(size_t)node * D + dim] = f2bf(aw[reg]);
                }
            }
        }
    }
}

// ---- pull+combine: out[n] = (1-z)*(meanY + bl + w) + z*h  (1 wave/node) ----
__global__ __launch_bounds__(256) void pull_kernel(
    const int* __restrict__ row_start, const int* __restrict__ deg,
    const int* __restrict__ col, const u16* __restrict__ y,
    const u16* __restrict__ z, const u16* __restrict__ w,
    const float* __restrict__ h, const float* __restrict__ bl,
    float* __restrict__ out, int N)
{
    const int wave = threadIdx.x >> 6;
    const int lane = threadIdx.x & 63;
    const int node = blockIdx.x * 4 + wave;
    if (node >= N) return;

    const int base = row_start[node];
    const int d    = deg[node];
    const int g    = lane >> 4;
    const int l15  = lane & 15;

    float a[8] = {0.f,0.f,0.f,0.f,0.f,0.f,0.f,0.f};
    for (int i = 0; i < d; i += 4) {
        int e = i + g;
        if (e < d) {
            int s = col[base + e];
            bf16x8 v = *(const bf16x8*)(y + (size_t)s * D + l15 * 8);
#pragma unroll
            for (int j = 0; j < 8; j++) a[j] += bf2f((u16)v[j]);
        }
    }
#pragma unroll
    for (int j = 0; j < 8; j++) {
        a[j] += __shfl_xor(a[j], 16, 64);
        a[j] += __shfl_xor(a[j], 32, 64);
    }
    if (lane < 16) {
        float inv = 1.0f / (float)(d > 0 ? d : 1);
        size_t o16 = (size_t)node * D + l15 * 8;
        bf16x8 zv = *(const bf16x8*)(z + o16);
        bf16x8 wv = *(const bf16x8*)(w + o16);
        f32x4 h0 = *(const f32x4*)(h + o16);
        f32x4 h1 = *(const f32x4*)(h + o16 + 4);
        f32x4 b0 = *(const f32x4*)(bl + l15 * 8);
        f32x4 b1 = *(const f32x4*)(bl + l15 * 8 + 4);
        f32x4 o0, o1;
#pragma unroll
        for (int j = 0; j < 4; j++) {
            float zz = bf2f((u16)zv[j]);
            float nv = a[j] * inv + b0[j] + bf2f((u16)wv[j]);
            o0[j] = (1.0f - zz) * nv + zz * h0[j];
        }
#pragma unroll
        for (int j = 0; j < 4; j++) {
            float zz = bf2f((u16)zv[j + 4]);
            float nv = a[j + 4] * inv + b1[j] + bf2f((u16)wv[j + 4]);
            o1[j] = (1.0f - zz) * nv + zz * h1[j];
        }
        *(f32x4*)(out + o16)     = o0;
        *(f32x4*)(out + o16 + 4) = o1;
    }
}

extern "C" void kernel_launch(void* const* d_in, const int* in_sizes, int n_in,
                              void* d_out, int out_size, void* d_ws, size_t ws_size,
                              hipStream_t stream)
{
    const float* x   = (const float*)d_in[0];
    const int*   ei  = (const int*)d_in[1];
    const float* h   = (const float*)d_in[2];
    const float* Wxr = (const float*)d_in[3];
    const float* bxr = (const float*)d_in[4];
    const float* Whr = (const float*)d_in[5];
    const float* Wxz = (const float*)d_in[6];
    const float* bxz = (const float*)d_in[7];
    const float* Whz = (const float*)d_in[8];
    const float* Wl  = (const float*)d_in[9];
    const float* bl  = (const float*)d_in[10];
    const float* Wr  = (const float*)d_in[11];
    float* out = (float*)d_out;

    const int N = in_sizes[0] / D;
    const int E = in_sizes[1] / 2;
    if (N <= 0 || E <= 0) return;

    const int nbn = (N + 255) / 256;
    if (nbn > 256) return;                  // scan2 capacity; N=50000 ok

    char* ws = (char*)d_ws;
    size_t off = 0;
    auto alloc = [&](size_t bytes) -> void* {
        void* p = ws + off;
        off += (bytes + 255) & ~(size_t)255;
        return p;
    };
    u16*   z     = (u16*)  alloc((size_t)N * D * 2);
    u16*   xbuf  = (u16*)  alloc((size_t)N * D * 2);
    u16*   y     = (u16*)  alloc((size_t)N * D * 2);
    u16*   w     = (u16*)  alloc((size_t)N * D * 2);
    int*   deg   = (int*)  alloc((size_t)N * 4);
    int*   rstart= (int*)  alloc((size_t)N * 4);
    int*   fillc = (int*)  alloc((size_t)N * 4);
    int*   bsum  = (int*)  alloc((size_t)256 * 4);
    int*   col   = (int*)  alloc((size_t)E * 4);
    u16*   WxrT  = (u16*)  alloc((size_t)D * D * 2);
    u16*   WhrT  = (u16*)  alloc((size_t)D * D * 2);
    u16*   WxzT  = (u16*)  alloc((size_t)D * D * 2);
    u16*   WhzT  = (u16*)  alloc((size_t)D * D * 2);
    u16*   WlT   = (u16*)  alloc((size_t)DC * D * 2);
    u16*   WrT   = (u16*)  alloc((size_t)DC * D * 2);
    (void)n_in; (void)out_size;
    if (off > ws_size) return;   // clean failure instead of OOB fault

    hipMemsetAsync(deg, 0, (size_t)N * 4, stream);

    const int nbx = (N * D + 255) / 256;
    const int nbh = (E + 255) / 256;
    prep_kernel<<<512 + nbx + nbh, 256, 0, stream>>>(
        Wxr, Whr, Wxz, Whz, Wl, Wr,
        WxrT, WhrT, WxzT, WhzT, WlT, WrT,
        x, xbuf, ei, deg, N, E, nbx);

    scan1_kernel<<<nbn, 256, 0, stream>>>(deg, rstart, bsum, N);
    scan2_kernel<<<1, 256, 0, stream>>>(bsum, nbn);
    scan3_kernel<<<nbn, 256, 0, stream>>>(rstart, bsum, fillc, N);
    fill_kernel<<<nbh, 256, 0, stream>>>(ei, rstart, fillc, col, E);

    fused_kernel<<<(N + 127) / 128, 512, 0, stream>>>(
        xbuf, h, WxrT, WhrT, WxzT, WhzT, WlT, WrT, bxr, bxz, z, y, w, N);

    pull_kernel<<<(N + 3) / 4, 256, 0, stream>>>(
        rstart, deg, col, y, z, w, h, bl, out, N);
}

// Round 3
// 288.509 us; speedup vs baseline: 1.2910x; 1.0232x over previous
//
// Inputs f32 (+ int32 edge_index), output f32, bf16 MFMA internally.
// R15: fused -> 256 nodes/block (16 tiles), phase-sequential with rh held
// packed-bf16 in regs between phases (in-place LDS overwrite of dead h).
// Weight L2 traffic 100->50MB; xb A-frags L1-broadcast across 8 waves.
// pull: col prefetch + shfl (kills dependent load chain). prep vectorized
// 4 elems/thread. scan2+scan3 fused; fillc zeroed in the deg memset.
#include <hip/hip_runtime.h>
#include <hip/hip_bf16.h>

typedef __attribute__((ext_vector_type(8))) short bf16x8;
typedef __attribute__((ext_vector_type(4))) short s16x4;
typedef __attribute__((ext_vector_type(4))) float f32x4;
typedef __attribute__((ext_vector_type(4))) int i32x4;
typedef unsigned short u16;
typedef unsigned int u32;

#define D 128      // D_IN == D_H
#define DC 256     // concat dim
#define TILES 16   // node tiles per block (256 nodes)
// LDS tile: 16 rows x 128 u16, XOR-swizzled (16B-aligned, low bank conflict)
#define SWZ(row, dim) (((row) << 7) + ((dim) ^ (((row) & 15) << 3)))

__device__ __forceinline__ float bf2f(u16 b) {
    u32 u = ((u32)b) << 16;
    return __uint_as_float(u);
}
__device__ __forceinline__ u16 f2bf(float f) {
    u32 u = __float_as_uint(f);
    u32 r = (u + 0x7fffu + ((u >> 16) & 1u)) >> 16;   // RNE
    return (u16)r;
}
__device__ __forceinline__ float sigmoidf_(float x) {
    float e = __builtin_amdgcn_exp2f(-1.4426950408889634f * x);
    return __builtin_amdgcn_rcpf(1.0f + e);
}
__device__ __forceinline__ bf16x8 cvt8(const float* __restrict__ p) {
    f32x4 lo = *(const f32x4*)p;
    f32x4 hi = *(const f32x4*)(p + 4);
    union { bf16x8 v; u16 s[8]; } u;
#pragma unroll
    for (int i = 0; i < 4; i++) {
        u.s[i]     = f2bf(lo[i]);
        u.s[i + 4] = f2bf(hi[i]);
    }
    return u.v;
}

// Fused prep (4 elems/thread): 6 weight transposes (f32->bf16) + xb=bf16(x)
// + degree histogram. Grid: [0,64) gate W, [64,128) Wl/Wr, then xb, then hist.
__global__ __launch_bounds__(256) void prep_kernel(
    const float* __restrict__ Wxr, const float* __restrict__ Whr,
    const float* __restrict__ Wxz, const float* __restrict__ Whz,
    const float* __restrict__ Wl,  const float* __restrict__ Wr,
    u16* __restrict__ WxrT, u16* __restrict__ WhrT,
    u16* __restrict__ WxzT, u16* __restrict__ WhzT,
    u16* __restrict__ WlT,  u16* __restrict__ WrT,
    const float* __restrict__ x, u16* __restrict__ xb,
    const int* __restrict__ ei, int* __restrict__ deg,
    int N, int E, int nbx4)
{
    int bid = blockIdx.x;
    int tid = threadIdx.x;
    if (bid < 64) {                        // 4 gate weights, 128x128, 16 blocks each
        int m = bid >> 4;
        int idx = (bid & 15) * 1024 + tid * 4;
        const float* W = (m == 0) ? Wxr : (m == 1) ? Whr : (m == 2) ? Wxz : Whz;
        u16* Wt        = (m == 0) ? WxrT : (m == 1) ? WhrT : (m == 2) ? WxzT : WhzT;
        f32x4 v = *(const f32x4*)(W + idx);
        int k = idx >> 7, n = idx & 127;
#pragma unroll
        for (int j = 0; j < 4; j++) Wt[(n + j) * D + k] = f2bf(v[j]);
    } else if (bid < 128) {                // Wl / Wr, 256x128, 32 blocks each
        int m = (bid - 64) >> 5;
        int idx = ((bid - 64) & 31) * 1024 + tid * 4;
        const float* W = (m == 0) ? Wl : Wr;
        u16* Wt        = (m == 0) ? WlT : WrT;
        f32x4 v = *(const f32x4*)(W + idx);
        int k = idx >> 7, n = idx & 127;
#pragma unroll
        for (int j = 0; j < 4; j++) Wt[(n + j) * DC + k] = f2bf(v[j]);
    } else if (bid < 128 + nbx4) {         // xb = bf16(x), 4/thread
        long long g = ((long long)(bid - 128) * 256 + tid) * 4;
        if (g + 3 < (long long)N * D) {
            f32x4 v = *(const f32x4*)(x + g);
            union { s16x4 s4; u16 s[4]; } o;
#pragma unroll
            for (int j = 0; j < 4; j++) o.s[j] = f2bf(v[j]);
            *(s16x4*)(xb + g) = o.s4;
        } else {
            for (int j = 0; j < 4 && g + j < (long long)N * D; j++)
                xb[g + j] = f2bf(x[g + j]);
        }
    } else {                               // histogram of dst, 4/thread
        long long e = ((long long)(bid - 128 - nbx4) * 256 + tid) * 4;
        if (e + 3 < E) {
            i32x4 d4 = *(const i32x4*)(ei + (size_t)E + e);
#pragma unroll
            for (int j = 0; j < 4; j++) atomicAdd(&deg[d4[j]], 1);
        } else {
            for (int j = 0; j < 4 && e + j < E; j++)
                atomicAdd(&deg[ei[(size_t)E + e + j]], 1);
        }
    }
}

// ---- parallel exclusive scan of deg -> rstart ----
__global__ __launch_bounds__(256) void scan1_kernel(
    const int* __restrict__ deg, int* __restrict__ rstart,
    int* __restrict__ bsum, int N)
{
    __shared__ int tmp[256];
    int t = threadIdx.x;
    int g = blockIdx.x * 256 + t;
    int v = (g < N) ? deg[g] : 0;
    tmp[t] = v;
    __syncthreads();
#pragma unroll
    for (int s = 1; s < 256; s <<= 1) {
        int add = (t >= s) ? tmp[t - s] : 0;
        __syncthreads();
        tmp[t] += add;
        __syncthreads();
    }
    if (g < N) rstart[g] = tmp[t] - v;
    if (t == 255) bsum[blockIdx.x] = tmp[255];
}

// scan2+scan3 fused: each block redundantly scans bsum (nbn<=256) and adds
// its exclusive block prefix to rstart.
__global__ __launch_bounds__(256) void scan23_kernel(
    int* __restrict__ rstart, const int* __restrict__ bsum, int N, int nbn)
{
    __shared__ int tmp[256];
    int t = threadIdx.x;
    int v = (t < nbn) ? bsum[t] : 0;
    tmp[t] = v;
    __syncthreads();
#pragma unroll
    for (int s = 1; s < 256; s <<= 1) {
        int add = (t >= s) ? tmp[t - s] : 0;
        __syncthreads();
        tmp[t] += add;
        __syncthreads();
    }
    int b = blockIdx.x;
    int excl = tmp[b] - ((b < nbn) ? bsum[b] : 0);
    int g = b * 256 + t;
    if (g < N) rstart[g] += excl;
}

__global__ void fill_kernel(const int* __restrict__ ei, const int* __restrict__ row_start,
                            int* __restrict__ fillc, int* __restrict__ col, int E) {
    int e = blockIdx.x * 256 + threadIdx.x;
    if (e >= E) return;
    int src = ei[e], dst = ei[(size_t)E + e];
    int pos = atomicAdd(&fillc[dst], 1);
    col[row_start[dst] + pos] = src;
}

// ---- fused: gates (r,z) -> rh (regs) -> y=[xb|rh]@Wl, w=[xb|rh]@Wr ----
// 512 threads = 8 waves; 256 nodes (16 tiles) per block. Wave w owns output
// dims [w*16, w*16+16) for ALL tiles. Phase-sequential: gates for all tiles
// (rh packed bf16 in regs), barrier, rh -> LDS in place of dead h, barrier,
// proj for all tiles. Gate/proj weight frags time-share registers.
__global__ __launch_bounds__(512, 2) void fused_kernel(
    const u16* __restrict__ xb, const float* __restrict__ h,
    const u16* __restrict__ WxrT, const u16* __restrict__ WhrT,
    const u16* __restrict__ WxzT, const u16* __restrict__ WhzT,
    const u16* __restrict__ WlT,  const u16* __restrict__ WrT,
    const float* __restrict__ bxr, const float* __restrict__ bxz,
    u16* __restrict__ zo, u16* __restrict__ yo, u16* __restrict__ wo, int N)
{
    __shared__ u16 hT[TILES][16 * 128];    // 64KB: h tiles, then rh in place
    const int wave = threadIdx.x >> 6;
    const int lane = threadIdx.x & 63;
    const int quad = lane >> 4;
    const int l15  = lane & 15;
    const int node0 = blockIdx.x * (TILES * 16);
    if (node0 >= N) return;

    // stage h tiles (each wave stages 2): coalesced f32 reads -> bf16 swz LDS
#pragma unroll
    for (int tt = 0; tt < 2; tt++) {
        int t = wave * 2 + tt;
        u16* Lh = hT[t];
        int tb = node0 + t * 16;
#pragma unroll
        for (int it = 0; it < 4; it++) {
            int idx = it * 64 + lane;
            int row = idx >> 4, seg = idx & 15;
            int node = tb + row; if (node >= N) node = N - 1;
            *(bf16x8*)&Lh[SWZ(row, seg * 8)] = cvt8(h + (size_t)node * D + seg * 8);
        }
    }
    __syncthreads();

    const int dim = wave * 16 + l15;       // this wave's output dim
    u32 rhp0[TILES], rhp1[TILES];          // rh packed bf16x2, static-indexed

    // ---- gates phase: all tiles ----
    {
        const u16* wrx = WxrT + (size_t)dim * D + quad * 8;
        const u16* wrh = WhrT + (size_t)dim * D + quad * 8;
        const u16* wzx = WxzT + (size_t)dim * D + quad * 8;
        const u16* wzh = WhzT + (size_t)dim * D + quad * 8;
        bf16x8 b0[4], b1[4], b2[4], b3[4];
#pragma unroll
        for (int c = 0; c < 4; c++) {
            b0[c] = *(const bf16x8*)(wrx + c * 32);
            b1[c] = *(const bf16x8*)(wrh + c * 32);
            b2[c] = *(const bf16x8*)(wzx + c * 32);
            b3[c] = *(const bf16x8*)(wzh + c * 32);
        }
        float br = bxr[dim];
        float bz = bxz[dim];
#pragma unroll
        for (int t = 0; t < TILES; t++) {
            const u16* Lh = hT[t];
            int tb = node0 + t * 16;
            int arow = tb + l15; if (arow >= N) arow = N - 1;
            const u16* xp = xb + (size_t)arow * D + quad * 8;
            bf16x8 ax[4], ah[4];
#pragma unroll
            for (int c = 0; c < 4; c++) {
                ax[c] = *(const bf16x8*)(xp + c * 32);
                ah[c] = *(const bf16x8*)&Lh[SWZ(l15, c * 32 + quad * 8)];
            }
            f32x4 ar = {0.f,0.f,0.f,0.f};
            f32x4 az = {0.f,0.f,0.f,0.f};
#pragma unroll
            for (int c = 0; c < 4; c++) {
                ar = __builtin_amdgcn_mfma_f32_16x16x32_bf16(ax[c], b0[c], ar, 0, 0, 0);
                ar = __builtin_amdgcn_mfma_f32_16x16x32_bf16(ah[c], b1[c], ar, 0, 0, 0);
                az = __builtin_amdgcn_mfma_f32_16x16x32_bf16(ax[c], b2[c], az, 0, 0, 0);
                az = __builtin_amdgcn_mfma_f32_16x16x32_bf16(ah[c], b3[c], az, 0, 0, 0);
            }
            u32 p0 = 0, p1 = 0;
#pragma unroll
            for (int reg = 0; reg < 4; reg++) {
                int row = quad * 4 + reg;
                int node = tb + row;
                float hv = bf2f(Lh[SWZ(row, dim)]);
                float r  = sigmoidf_(ar[reg] + br);
                float zz = sigmoidf_(az[reg] + bz);
                u32 rh = f2bf(r * hv);
                if (reg == 0) p0 = rh;
                else if (reg == 1) p0 |= rh << 16;
                else if (reg == 2) p1 = rh;
                else p1 |= rh << 16;
                if (node < N) zo[(size_t)node * D + dim] = f2bf(zz);
            }
            rhp0[t] = p0;
            rhp1[t] = p1;
        }
    }
    __syncthreads();   // all reads of h done

    // write rh over dead h (each wave owns its dim column -> race-free)
#pragma unroll
    for (int t = 0; t < TILES; t++) {
        u16* Lh = hT[t];
        Lh[SWZ(quad * 4 + 0, dim)] = (u16)(rhp0[t]);
        Lh[SWZ(quad * 4 + 1, dim)] = (u16)(rhp0[t] >> 16);
        Lh[SWZ(quad * 4 + 2, dim)] = (u16)(rhp1[t]);
        Lh[SWZ(quad * 4 + 3, dim)] = (u16)(rhp1[t] >> 16);
    }
    __syncthreads();   // all rh tiles complete

    // ---- proj phase: y = [xb|rh] @ Wl, w = [xb|rh] @ Wr ----
    {
        const u16* pl = WlT + (size_t)dim * DC + quad * 8;
        const u16* pr = WrT + (size_t)dim * DC + quad * 8;
        bf16x8 l0[4], l1[4], r0[4], r1[4];
#pragma unroll
        for (int c = 0; c < 4; c++) {
            l0[c] = *(const bf16x8*)(pl + c * 32);
            l1[c] = *(const bf16x8*)(pl + 128 + c * 32);
            r0[c] = *(const bf16x8*)(pr + c * 32);
            r1[c] = *(const bf16x8*)(pr + 128 + c * 32);
        }
#pragma unroll
        for (int t = 0; t < TILES; t++) {
            const u16* Lrh = hT[t];
            int tb = node0 + t * 16;
            int arow = tb + l15; if (arow >= N) arow = N - 1;
            const u16* xp = xb + (size_t)arow * D + quad * 8;
            bf16x8 ax[4], arh[4];
#pragma unroll
            for (int c = 0; c < 4; c++) {
                ax[c]  = *(const bf16x8*)(xp + c * 32);
                arh[c] = *(const bf16x8*)&Lrh[SWZ(l15, c * 32 + quad * 8)];
            }
            f32x4 ay = {0.f,0.f,0.f,0.f};
            f32x4 aw = {0.f,0.f,0.f,0.f};
#pragma unroll
            for (int c = 0; c < 4; c++) {
                ay = __builtin_amdgcn_mfma_f32_16x16x32_bf16(ax[c],  l0[c], ay, 0, 0, 0);
                ay = __builtin_amdgcn_mfma_f32_16x16x32_bf16(arh[c], l1[c], ay, 0, 0, 0);
                aw = __builtin_amdgcn_mfma_f32_16x16x32_bf16(ax[c],  r0[c], aw, 0, 0, 0);
                aw = __builtin_amdgcn_mfma_f32_16x16x32_bf16(arh[c], r1[c], aw, 0, 0, 0);
            }
#pragma unroll
            for (int reg = 0; reg < 4; reg++) {
                int row = quad * 4 + reg;
                int node = tb + row;
                if (node < N) {
                    yo[(size_t)node * D + dim] = f2bf(ay[reg]);
                    wo[(size_t)node * D + dim] = f2bf(aw[reg]);
                }
            }
        }
    }
}

// ---- pull+combine: out[n] = (1-z)*(meanY + bl + w) + z*h  (1 wave/node) ----
// col entries prefetched into one register and shfl-distributed: removes the
// dependent col->gather load chain (d<=64 covers ~all nodes at avg degree 16).
__global__ __launch_bounds__(256) void pull_kernel(
    const int* __restrict__ row_start, const int* __restrict__ deg,
    const int* __restrict__ col, const u16* __restrict__ y,
    const u16* __restrict__ z, const u16* __restrict__ w,
    const float* __restrict__ h, const float* __restrict__ bl,
    float* __restrict__ out, int N)
{
    const int wave = threadIdx.x >> 6;
    const int lane = threadIdx.x & 63;
    const int node = blockIdx.x * 4 + wave;
    if (node >= N) return;

    const int base = row_start[node];
    const int d    = deg[node];
    const int g    = lane >> 4;
    const int l15  = lane & 15;

    const int dcap = (d < 64) ? d : 64;
    int cols = 0;
    if (lane < dcap) cols = col[base + lane];

    float a[8] = {0.f,0.f,0.f,0.f,0.f,0.f,0.f,0.f};
    for (int i = 0; i < dcap; i += 4) {
        int e = i + g;
        int s = __shfl(cols, e & 63, 64);
        if (e < dcap) {
            bf16x8 v = *(const bf16x8*)(y + (size_t)s * D + l15 * 8);
#pragma unroll
            for (int j = 0; j < 8; j++) a[j] += bf2f((u16)v[j]);
        }
    }
    for (int i = 64; i < d; i += 4) {      // rare heavy-degree tail
        int e = i + g;
        if (e < d) {
            int s = col[base + e];
            bf16x8 v = *(const bf16x8*)(y + (size_t)s * D + l15 * 8);
#pragma unroll
            for (int j = 0; j < 8; j++) a[j] += bf2f((u16)v[j]);
        }
    }
#pragma unroll
    for (int j = 0; j < 8; j++) {
        a[j] += __shfl_xor(a[j], 16, 64);
        a[j] += __shfl_xor(a[j], 32, 64);
    }
    if (lane < 16) {
        float inv = 1.0f / (float)(d > 0 ? d : 1);
        size_t o16 = (size_t)node * D + l15 * 8;
        bf16x8 zv = *(const bf16x8*)(z + o16);
        bf16x8 wv = *(const bf16x8*)(w + o16);
        f32x4 h0 = *(const f32x4*)(h + o16);
        f32x4 h1 = *(const f32x4*)(h + o16 + 4);
        f32x4 b0 = *(const f32x4*)(bl + l15 * 8);
        f32x4 b1 = *(const f32x4*)(bl + l15 * 8 + 4);
        f32x4 o0, o1;
#pragma unroll
        for (int j = 0; j < 4; j++) {
            float zz = bf2f((u16)zv[j]);
            float nv = a[j] * inv + b0[j] + bf2f((u16)wv[j]);
            o0[j] = (1.0f - zz) * nv + zz * h0[j];
        }
#pragma unroll
        for (int j = 0; j < 4; j++) {
            float zz = bf2f((u16)zv[j + 4]);
            float nv = a[j + 4] * inv + b1[j] + bf2f((u16)wv[j + 4]);
            o1[j] = (1.0f - zz) * nv + zz * h1[j];
        }
        *(f32x4*)(out + o16)     = o0;
        *(f32x4*)(out + o16 + 4) = o1;
    }
}

extern "C" void kernel_launch(void* const* d_in, const int* in_sizes, int n_in,
                              void* d_out, int out_size, void* d_ws, size_t ws_size,
                              hipStream_t stream)
{
    const float* x   = (const float*)d_in[0];
    const int*   ei  = (const int*)d_in[1];
    const float* h   = (const float*)d_in[2];
    const float* Wxr = (const float*)d_in[3];
    const float* bxr = (const float*)d_in[4];
    const float* Whr = (const float*)d_in[5];
    const float* Wxz = (const float*)d_in[6];
    const float* bxz = (const float*)d_in[7];
    const float* Whz = (const float*)d_in[8];
    const float* Wl  = (const float*)d_in[9];
    const float* bl  = (const float*)d_in[10];
    const float* Wr  = (const float*)d_in[11];
    float* out = (float*)d_out;

    const int N = in_sizes[0] / D;
    const int E = in_sizes[1] / 2;
    if (N <= 0 || E <= 0) return;

    const int nbn = (N + 255) / 256;
    if (nbn > 256) return;                  // scan23 capacity; N=50000 ok

    char* ws = (char*)d_ws;
    size_t off = 0;
    auto alloc = [&](size_t bytes) -> void* {
        void* p = ws + off;
        off += (bytes + 255) & ~(size_t)255;
        return p;
    };
    u16*   z     = (u16*)  alloc((size_t)N * D * 2);
    u16*   xbuf  = (u16*)  alloc((size_t)N * D * 2);
    u16*   y     = (u16*)  alloc((size_t)N * D * 2);
    u16*   w     = (u16*)  alloc((size_t)N * D * 2);
    int*   deg   = (int*)  alloc((size_t)N * 4);     // deg+fillc adjacent:
    int*   fillc = (int*)  alloc((size_t)N * 4);     // one memset covers both
    int*   rstart= (int*)  alloc((size_t)N * 4);
    int*   bsum  = (int*)  alloc((size_t)256 * 4);
    int*   col   = (int*)  alloc((size_t)E * 4);
    u16*   WxrT  = (u16*)  alloc((size_t)D * D * 2);
    u16*   WhrT  = (u16*)  alloc((size_t)D * D * 2);
    u16*   WxzT  = (u16*)  alloc((size_t)D * D * 2);
    u16*   WhzT  = (u16*)  alloc((size_t)D * D * 2);
    u16*   WlT   = (u16*)  alloc((size_t)DC * D * 2);
    u16*   WrT   = (u16*)  alloc((size_t)DC * D * 2);
    (void)n_in; (void)out_size;
    if (off > ws_size) return;   // clean failure instead of OOB fault

    hipMemsetAsync(deg, 0, (size_t)((char*)fillc - (char*)deg) + (size_t)N * 4, stream);

    const int nbx4 = (N * D + 1023) / 1024;
    const int nbh4 = (E + 1023) / 1024;
    prep_kernel<<<128 + nbx4 + nbh4, 256, 0, stream>>>(
        Wxr, Whr, Wxz, Whz, Wl, Wr,
        WxrT, WhrT, WxzT, WhzT, WlT, WrT,
        x, xbuf, ei, deg, N, E, nbx4);

    scan1_kernel<<<nbn, 256, 0, stream>>>(deg, rstart, bsum, N);
    scan23_kernel<<<nbn, 256, 0, stream>>>(rstart, bsum, N, nbn);
    fill_kernel<<<(E + 255) / 256, 256, 0, stream>>>(ei, rstart, fillc, col, E);

    fused_kernel<<<(N + TILES * 16 - 1) / (TILES * 16), 512, 0, stream>>>(
        xbuf, h, WxrT, WhrT, WxzT, WhzT, WlT, WrT, bxr, bxz, z, y, w, N);

    pull_kernel<<<(N + 3) / 4, 256, 0, stream>>>(
        rstart, deg, col, y, z, w, h, bl, out, N);
}